// Round 3
// baseline (244.688 us; speedup 1.0000x reference)
//
#include <hip/hip_runtime.h>
#include <hip/hip_bf16.h>

#define BB 2
#define CC 512
#define CK 64
#define NN 4096  // D*W*H = 4*32*32

typedef short bf16x8 __attribute__((ext_vector_type(8)));
typedef short bf16x4 __attribute__((ext_vector_type(4)));
typedef float f32x4 __attribute__((ext_vector_type(4)));

#define L2E 1.4426950408889634f

__device__ __forceinline__ unsigned short f2bf(float f) {
    union { float f; unsigned u; } cvt; cvt.f = f;
    unsigned r = cvt.u + 0x7fff + ((cvt.u >> 16) & 1);  // RNE
    return (unsigned short)(r >> 16);
}

__device__ __forceinline__ float fast_exp2(float x) {
#if __has_builtin(__builtin_amdgcn_exp2f)
    return __builtin_amdgcn_exp2f(x);
#else
    return __expf(x * 0.6931471805599453f);
#endif
}

// ---------------------------------------------------------------------------
// K1: fused f/g projection via bf16 MFMA. fgT[b][n][k] (ushort bf16),
// k in [0,64)=fx*log2e (pre-scaled for exp2), [64,128)=gx.
// Block: 128 k x 16 n output tile -> grid 512 = 2 blocks/CU (hide barriers).
// Also zero-inits the row-sum buffer l (8192 floats) from the first 32 blocks.
// ---------------------------------------------------------------------------
__global__ __launch_bounds__(256) void proj_fg(
    const float* __restrict__ x,
    const float* __restrict__ f_w, const float* __restrict__ f_b,
    const float* __restrict__ g_w, const float* __restrict__ g_b,
    unsigned short* __restrict__ fgT, float* __restrict__ l)
{
    __shared__ unsigned short w_s[128][72];   // [k][c], +8 pad
    __shared__ unsigned short xT_s[16][72];   // [n][c]
    __shared__ float bias_s[128];
    const int t    = threadIdx.x;
    const int b    = blockIdx.y;
    const int n0   = blockIdx.x * 16;
    const int wave = t >> 6, lane = t & 63;
    const int quad = lane >> 4, tl = lane & 15;

    if (blockIdx.y == 0 && blockIdx.x < 32)   // zero l for attn_rowsum
        l[blockIdx.x * 256 + t] = 0.0f;
    if (t < 128)
        bias_s[t] = (t < CK) ? f_b[t] * L2E : g_b[t - CK];

    f32x4 acc[2] = {};  // [ktile = wave*2 + kt2]

    for (int c0 = 0; c0 < CC; c0 += 64) {
        // stage w: 128 k x 64 c, float4 global loads, bf16x4 LDS stores
        #pragma unroll
        for (int it = 0; it < 8; ++it) {
            int idx = t + it * 256;            // 0..2047
            int k   = idx >> 4;                // 0..127
            int c4  = (idx & 15) * 4;
            const float* src = (k < CK) ? (f_w + (size_t)k * CC)
                                        : (g_w + (size_t)(k - CK) * CC);
            float4 v = *(const float4*)(src + c0 + c4);
            float  s = (k < CK) ? L2E : 1.0f;
            bf16x4 w4;
            w4[0] = (short)f2bf(v.x * s);
            w4[1] = (short)f2bf(v.y * s);
            w4[2] = (short)f2bf(v.z * s);
            w4[3] = (short)f2bf(v.w * s);
            *(bf16x4*)&w_s[k][c4] = w4;
        }
        // stage x^T: 64 c x 16 n, one float4 per thread
        {
            int c  = t >> 2;                   // 0..63
            int n4 = (t & 3) * 4;
            float4 v = *(const float4*)(x + ((size_t)(b * CC + c0 + c)) * NN + n0 + n4);
            xT_s[n4 + 0][c] = f2bf(v.x);
            xT_s[n4 + 1][c] = f2bf(v.y);
            xT_s[n4 + 2][c] = f2bf(v.z);
            xT_s[n4 + 3][c] = f2bf(v.w);
        }
        __syncthreads();
        #pragma unroll
        for (int s = 0; s < 2; ++s) {          // two K=32 steps in this chunk
            bf16x8 af0 = *(const bf16x8*)&w_s[(wave * 2 + 0) * 16 + tl][s * 32 + quad * 8];
            bf16x8 af1 = *(const bf16x8*)&w_s[(wave * 2 + 1) * 16 + tl][s * 32 + quad * 8];
            bf16x8 bx  = *(const bf16x8*)&xT_s[tl][s * 32 + quad * 8];
            acc[0] = __builtin_amdgcn_mfma_f32_16x16x32_bf16(af0, bx, acc[0], 0, 0, 0);
            acc[1] = __builtin_amdgcn_mfma_f32_16x16x32_bf16(af1, bx, acc[1], 0, 0, 0);
        }
        __syncthreads();
    }
    // C layout: col n = tl, row k = quad*4 + r
    #pragma unroll
    for (int kt2 = 0; kt2 < 2; ++kt2) {
        int kbase = (wave * 2 + kt2) * 16 + quad * 4;
        float4 bias = *(const float4*)&bias_s[kbase];
        int n = n0 + tl;
        bf16x4 o;
        o[0] = (short)f2bf(acc[kt2][0] + bias.x);
        o[1] = (short)f2bf(acc[kt2][1] + bias.y);
        o[2] = (short)f2bf(acc[kt2][2] + bias.z);
        o[3] = (short)f2bf(acc[kt2][3] + bias.w);
        *(bf16x4*)&fgT[(size_t)(b * NN + n) * 128 + kbase] = o;
    }
}

// ---------------------------------------------------------------------------
// K2a: per-row sum of exp2(energy'). Swapped operands: D[j][i], lane owns row
// i=tl; reduce over quads with 2 shfl_xor, coalesced atomics.
// ---------------------------------------------------------------------------
__global__ __launch_bounds__(256) void attn_rowsum(
    const unsigned short* __restrict__ fgT, float* __restrict__ l)
{
    const int b    = blockIdx.z;
    const int wave = threadIdx.x >> 6;
    const int lane = threadIdx.x & 63;
    const int quad = lane >> 4, tl = lane & 15;
    const int ibase = blockIdx.y * 256 + wave * 64;  // 4 i-tiles of 16
    const int j0    = blockIdx.x * 256;

    bf16x8 bf[4][2];
    #pragma unroll
    for (int it = 0; it < 4; ++it) {
        const unsigned short* row = fgT + (size_t)(b * NN + ibase + it * 16 + tl) * 128;
        bf[it][0] = *(const bf16x8*)(row + quad * 8);
        bf[it][1] = *(const bf16x8*)(row + 32 + quad * 8);
    }
    float part[4] = {0.f, 0.f, 0.f, 0.f};
    for (int jt = 0; jt < 256; jt += 16) {
        const unsigned short* grow = fgT + (size_t)(b * NN + j0 + jt + tl) * 128 + 64;
        bf16x8 a0 = *(const bf16x8*)(grow + quad * 8);
        bf16x8 a1 = *(const bf16x8*)(grow + 32 + quad * 8);
        #pragma unroll
        for (int it = 0; it < 4; ++it) {
            f32x4 acc = {0.f, 0.f, 0.f, 0.f};
            acc = __builtin_amdgcn_mfma_f32_16x16x32_bf16(a0, bf[it][0], acc, 0, 0, 0);
            acc = __builtin_amdgcn_mfma_f32_16x16x32_bf16(a1, bf[it][1], acc, 0, 0, 0);
            part[it] += fast_exp2(acc[0]) + fast_exp2(acc[1])
                      + fast_exp2(acc[2]) + fast_exp2(acc[3]);
        }
    }
    #pragma unroll
    for (int it = 0; it < 4; ++it) {
        float v = part[it];
        v += __shfl_xor(v, 16, 64);
        v += __shfl_xor(v, 32, 64);
        if (quad == 0)
            atomicAdd(&l[b * NN + ibase + it * 16 + tl], v);
    }
}

// ---------------------------------------------------------------------------
// K2b: recompute energy', write attention = exp2(e')/l_i with float4 stores.
// blockIdx.y in [64,66): fused out=x float4 copy (gamma==0 fast path).
// ---------------------------------------------------------------------------
__global__ __launch_bounds__(256) void attn_write(
    const unsigned short* __restrict__ fgT, const float* __restrict__ l,
    const float* __restrict__ gamma, const float* __restrict__ x,
    float* __restrict__ out, float* __restrict__ attn)
{
    const int b = blockIdx.z;
    if (blockIdx.y >= 64) {                    // fused residual-copy blocks
        if (gamma[0] != 0.0f) return;          // out_kernel handles slow path
        int cb = ((b * 2 + (blockIdx.y - 64)) * 8 + blockIdx.x) * 256 + threadIdx.x;
        const float4* xs = (const float4*)x;
        float4*       od = (float4*)out;
        #pragma unroll 4
        for (int i = cb; i < BB * CC * NN / 4; i += 32 * 256)
            od[i] = xs[i];
        return;
    }
    const int wave = threadIdx.x >> 6;
    const int lane = threadIdx.x & 63;
    const int quad = lane >> 4, tl = lane & 15;
    const int i    = blockIdx.y * 64 + wave * 16 + tl;
    const int j0   = blockIdx.x * 512;

    const unsigned short* frow = fgT + (size_t)(b * NN + i) * 128;
    bf16x8 b0 = *(const bf16x8*)(frow + quad * 8);
    bf16x8 b1 = *(const bf16x8*)(frow + 32 + quad * 8);
    const float inv = 1.0f / l[b * NN + i];

    float* orow = attn + (size_t)(b * NN + i) * NN + j0 + quad * 4;
    for (int jt = 0; jt < 512; jt += 16) {
        const unsigned short* grow = fgT + (size_t)(b * NN + j0 + jt + tl) * 128 + 64;
        bf16x8 a0 = *(const bf16x8*)(grow + quad * 8);
        bf16x8 a1 = *(const bf16x8*)(grow + 32 + quad * 8);
        f32x4 acc = {0.f, 0.f, 0.f, 0.f};
        acc = __builtin_amdgcn_mfma_f32_16x16x32_bf16(a0, b0, acc, 0, 0, 0);
        acc = __builtin_amdgcn_mfma_f32_16x16x32_bf16(a1, b1, acc, 0, 0, 0);
        float4 v;
        v.x = fast_exp2(acc[0]) * inv;
        v.y = fast_exp2(acc[1]) * inv;
        v.z = fast_exp2(acc[2]) * inv;
        v.w = fast_exp2(acc[3]) * inv;
        *(float4*)(orow + jt) = v;
    }
}

// ---------------------------------------------------------------------------
// hx projection — only needed when gamma != 0 (never in this bench; early-exit)
// ---------------------------------------------------------------------------
__global__ __launch_bounds__(256) void proj_h(
    const float* __restrict__ x, const float* __restrict__ h_w,
    const float* __restrict__ h_b, const float* __restrict__ gamma,
    float* __restrict__ hx)
{
    if (gamma[0] == 0.0f) return;
    int tid = blockIdx.x * 256 + threadIdx.x;   // 131072 threads
    for (int e = 0; e < 32; ++e) {
        int idx = tid + e * 131072;
        int n = idx & (NN - 1);
        int c = (idx >> 12) & (CC - 1);
        int b = idx >> 21;
        float s = h_b[c];
        for (int cc = 0; cc < CC; ++cc)
            s += h_w[c * CC + cc] * x[((size_t)b * CC + cc) * NN + n];
        hx[idx] = s;
    }
}

// ---------------------------------------------------------------------------
// gamma != 0 fallback: out = gamma * (hx . attn^T) + x. Early-exit when 0.
// ---------------------------------------------------------------------------
__global__ __launch_bounds__(256) void out_kernel(
    const float* __restrict__ x, const float* __restrict__ gamma,
    const float* __restrict__ hx, const float* __restrict__ attn,
    float* __restrict__ out)
{
    const float g = gamma[0];
    if (g == 0.0f) return;                      // copy fused into attn_write
    int tid = blockIdx.x * 256 + threadIdx.x;   // 524288 threads
    for (int e = 0; e < 8; ++e) {
        int idx = tid + e * 524288;
        int i = idx & (NN - 1);
        int c = (idx >> 12) & (CC - 1);
        int b = idx >> 21;
        const float* hrow = hx + ((size_t)b * CC + c) * NN;
        const float* arow = attn + ((size_t)b * NN + i) * NN;
        float s = 0.0f;
        for (int j = 0; j < NN; ++j) s += hrow[j] * arow[j];
        out[idx] = g * s + x[idx];
    }
}

extern "C" void kernel_launch(void* const* d_in, const int* in_sizes, int n_in,
                              void* d_out, int out_size, void* d_ws, size_t ws_size,
                              hipStream_t stream)
{
    (void)in_sizes; (void)n_in; (void)out_size; (void)ws_size;
    const float* x     = (const float*)d_in[0];
    const float* f_w   = (const float*)d_in[1];
    const float* f_b   = (const float*)d_in[2];
    const float* g_w   = (const float*)d_in[3];
    const float* g_b   = (const float*)d_in[4];
    const float* h_w   = (const float*)d_in[5];
    const float* h_b   = (const float*)d_in[6];
    const float* gamma = (const float*)d_in[7];

    float* out  = (float*)d_out;                 // [B,C,N] = 4,194,304 f32
    float* attn = out + (size_t)BB * CC * NN;    // [B,N,N] = 33,554,432 f32

    char* ws = (char*)d_ws;
    unsigned short* fgT = (unsigned short*)ws;                        // 2 MB
    float* l  = (float*)(ws + (size_t)BB * NN * 128 * 2);             // 32 KB
    float* hx = (float*)(ws + (size_t)BB * NN * 128 * 2 + 65536);     // 16 MB (dead path)

    proj_fg<<<dim3(NN / 16, BB), 256, 0, stream>>>(x, f_w, f_b, g_w, g_b, fgT, l);
    proj_h<<<512, 256, 0, stream>>>(x, h_w, h_b, gamma, hx);
    attn_rowsum<<<dim3(16, 16, 2), 256, 0, stream>>>(fgT, l);
    attn_write<<<dim3(8, 66, 2), 256, 0, stream>>>(fgT, l, gamma, x, out, attn);
    out_kernel<<<2048, 256, 0, stream>>>(x, gamma, hx, attn, out);
}

// Round 4
// 240.208 us; speedup vs baseline: 1.0187x; 1.0187x over previous
//
#include <hip/hip_runtime.h>
#include <hip/hip_bf16.h>

#define BB 2
#define CC 512
#define CK 64
#define NN 4096  // D*W*H = 4*32*32

typedef short bf16x8 __attribute__((ext_vector_type(8)));
typedef short bf16x4 __attribute__((ext_vector_type(4)));
typedef float f32x4 __attribute__((ext_vector_type(4)));

#define L2E 1.4426950408889634f

__device__ __forceinline__ unsigned short f2bf(float f) {
    union { float f; unsigned u; } cvt; cvt.f = f;
    unsigned r = cvt.u + 0x7fff + ((cvt.u >> 16) & 1);  // RNE
    return (unsigned short)(r >> 16);
}

__device__ __forceinline__ float fast_exp2(float x) {
#if __has_builtin(__builtin_amdgcn_exp2f)
    return __builtin_amdgcn_exp2f(x);
#else
    return __expf(x * 0.6931471805599453f);
#endif
}

// ---------------------------------------------------------------------------
// K1: fused f/g projection via bf16 MFMA. fgT[b][n][k] (ushort bf16),
// k in [0,64)=fx*log2e (pre-scaled for exp2), [64,128)=gx.
// Block: 128 k x 32 n output tile (grid 256 — R2 config, empirically best:
// halving the n-tile doubled weight-staging work and regressed).
// Also zero-inits the row-sum buffer l (8192 floats) from the first 32 blocks.
// ---------------------------------------------------------------------------
__global__ __launch_bounds__(256) void proj_fg(
    const float* __restrict__ x,
    const float* __restrict__ f_w, const float* __restrict__ f_b,
    const float* __restrict__ g_w, const float* __restrict__ g_b,
    unsigned short* __restrict__ fgT, float* __restrict__ l)
{
    __shared__ unsigned short w_s[128][72];   // [k][c], +8 pad: b128 reads 2-way (free)
    __shared__ unsigned short xT_s[32][72];   // [n][c]
    __shared__ float bias_s[128];
    const int t    = threadIdx.x;
    const int b    = blockIdx.y;
    const int n0   = blockIdx.x * 32;
    const int wave = t >> 6, lane = t & 63;
    const int quad = lane >> 4, tl = lane & 15;

    if (blockIdx.y == 0 && blockIdx.x < 32)   // zero l for attn_rowsum
        l[blockIdx.x * 256 + t] = 0.0f;
    if (t < 128)
        bias_s[t] = (t < CK) ? f_b[t] * L2E : g_b[t - CK];

    f32x4 acc[2][2] = {};  // [ktile 2w+kt2][ntile]

    for (int c0 = 0; c0 < CC; c0 += 64) {
        // stage w: 128 k x 64 c, float4 global loads, bf16x4 LDS stores
        #pragma unroll
        for (int it = 0; it < 8; ++it) {
            int idx = t + it * 256;            // 0..2047
            int k   = idx >> 4;                // 0..127
            int c4  = (idx & 15) * 4;
            const float* src = (k < CK) ? (f_w + (size_t)k * CC)
                                        : (g_w + (size_t)(k - CK) * CC);
            float4 v = *(const float4*)(src + c0 + c4);
            float  s = (k < CK) ? L2E : 1.0f;
            bf16x4 w4;
            w4[0] = (short)f2bf(v.x * s);
            w4[1] = (short)f2bf(v.y * s);
            w4[2] = (short)f2bf(v.z * s);
            w4[3] = (short)f2bf(v.w * s);
            *(bf16x4*)&w_s[k][c4] = w4;
        }
        // stage x^T: 64 c x 32 n, float4 loads along n, scalar transposed stores
        #pragma unroll
        for (int it = 0; it < 2; ++it) {
            int idx = t + it * 256;            // 0..511
            int c   = idx >> 3;                // 0..63
            int n4  = (idx & 7) * 4;
            float4 v = *(const float4*)(x + ((size_t)(b * CC + c0 + c)) * NN + n0 + n4);
            xT_s[n4 + 0][c] = f2bf(v.x);
            xT_s[n4 + 1][c] = f2bf(v.y);
            xT_s[n4 + 2][c] = f2bf(v.z);
            xT_s[n4 + 3][c] = f2bf(v.w);
        }
        __syncthreads();
        #pragma unroll
        for (int s = 0; s < 2; ++s) {          // two K=32 steps in this chunk
            bf16x8 af0 = *(const bf16x8*)&w_s[(wave * 2 + 0) * 16 + tl][s * 32 + quad * 8];
            bf16x8 af1 = *(const bf16x8*)&w_s[(wave * 2 + 1) * 16 + tl][s * 32 + quad * 8];
            bf16x8 bx0 = *(const bf16x8*)&xT_s[tl][s * 32 + quad * 8];
            bf16x8 bx1 = *(const bf16x8*)&xT_s[16 + tl][s * 32 + quad * 8];
            acc[0][0] = __builtin_amdgcn_mfma_f32_16x16x32_bf16(af0, bx0, acc[0][0], 0, 0, 0);
            acc[0][1] = __builtin_amdgcn_mfma_f32_16x16x32_bf16(af0, bx1, acc[0][1], 0, 0, 0);
            acc[1][0] = __builtin_amdgcn_mfma_f32_16x16x32_bf16(af1, bx0, acc[1][0], 0, 0, 0);
            acc[1][1] = __builtin_amdgcn_mfma_f32_16x16x32_bf16(af1, bx1, acc[1][1], 0, 0, 0);
        }
        __syncthreads();
    }
    // C layout: col n = tl, row k = quad*4 + r
    #pragma unroll
    for (int kt2 = 0; kt2 < 2; ++kt2) {
        int kbase = (wave * 2 + kt2) * 16 + quad * 4;
        float4 bias = *(const float4*)&bias_s[kbase];
        #pragma unroll
        for (int nt = 0; nt < 2; ++nt) {
            int n = n0 + nt * 16 + tl;
            bf16x4 o;
            o[0] = (short)f2bf(acc[kt2][nt][0] + bias.x);
            o[1] = (short)f2bf(acc[kt2][nt][1] + bias.y);
            o[2] = (short)f2bf(acc[kt2][nt][2] + bias.z);
            o[3] = (short)f2bf(acc[kt2][nt][3] + bias.w);
            *(bf16x4*)&fgT[(size_t)(b * NN + n) * 128 + kbase] = o;
        }
    }
}

// ---------------------------------------------------------------------------
// K2a: per-row sum of exp2(energy'). Operands swapped: D[j][i] so each lane
// owns a fixed row i=tl; reduce over quads with 2 shfl_xor, coalesced atomics.
// ---------------------------------------------------------------------------
__global__ __launch_bounds__(256) void attn_rowsum(
    const unsigned short* __restrict__ fgT, float* __restrict__ l)
{
    const int b    = blockIdx.z;
    const int wave = threadIdx.x >> 6;
    const int lane = threadIdx.x & 63;
    const int quad = lane >> 4, tl = lane & 15;
    const int ibase = blockIdx.y * 256 + wave * 64;  // 4 i-tiles of 16
    const int j0    = blockIdx.x * 256;

    bf16x8 bf[4][2];
    #pragma unroll
    for (int it = 0; it < 4; ++it) {
        const unsigned short* row = fgT + (size_t)(b * NN + ibase + it * 16 + tl) * 128;
        bf[it][0] = *(const bf16x8*)(row + quad * 8);
        bf[it][1] = *(const bf16x8*)(row + 32 + quad * 8);
    }
    float part[4] = {0.f, 0.f, 0.f, 0.f};
    for (int jt = 0; jt < 256; jt += 16) {
        const unsigned short* grow = fgT + (size_t)(b * NN + j0 + jt + tl) * 128 + 64;
        bf16x8 a0 = *(const bf16x8*)(grow + quad * 8);
        bf16x8 a1 = *(const bf16x8*)(grow + 32 + quad * 8);
        #pragma unroll
        for (int it = 0; it < 4; ++it) {
            f32x4 acc = {0.f, 0.f, 0.f, 0.f};
            acc = __builtin_amdgcn_mfma_f32_16x16x32_bf16(a0, bf[it][0], acc, 0, 0, 0);
            acc = __builtin_amdgcn_mfma_f32_16x16x32_bf16(a1, bf[it][1], acc, 0, 0, 0);
            part[it] += fast_exp2(acc[0]) + fast_exp2(acc[1])
                      + fast_exp2(acc[2]) + fast_exp2(acc[3]);
        }
    }
    #pragma unroll
    for (int it = 0; it < 4; ++it) {
        float v = part[it];
        v += __shfl_xor(v, 16, 64);
        v += __shfl_xor(v, 32, 64);
        if (quad == 0)
            atomicAdd(&l[b * NN + ibase + it * 16 + tl], v);
    }
}

// ---------------------------------------------------------------------------
// K2b: recompute energy', write attention = exp2(e')/l_i with float4 stores.
// Swapped operands: lane owns row i; regs r = 4 consecutive j.
// ---------------------------------------------------------------------------
__global__ __launch_bounds__(256) void attn_write(
    const unsigned short* __restrict__ fgT, const float* __restrict__ l,
    float* __restrict__ attn)
{
    const int b    = blockIdx.z;
    const int wave = threadIdx.x >> 6;
    const int lane = threadIdx.x & 63;
    const int quad = lane >> 4, tl = lane & 15;
    const int i    = blockIdx.y * 64 + wave * 16 + tl;
    const int j0   = blockIdx.x * 512;

    const unsigned short* frow = fgT + (size_t)(b * NN + i) * 128;
    bf16x8 b0 = *(const bf16x8*)(frow + quad * 8);
    bf16x8 b1 = *(const bf16x8*)(frow + 32 + quad * 8);
    const float inv = 1.0f / l[b * NN + i];

    float* orow = attn + (size_t)(b * NN + i) * NN + j0 + quad * 4;
    for (int jt = 0; jt < 512; jt += 16) {
        const unsigned short* grow = fgT + (size_t)(b * NN + j0 + jt + tl) * 128 + 64;
        bf16x8 a0 = *(const bf16x8*)(grow + quad * 8);
        bf16x8 a1 = *(const bf16x8*)(grow + 32 + quad * 8);
        f32x4 acc = {0.f, 0.f, 0.f, 0.f};
        acc = __builtin_amdgcn_mfma_f32_16x16x32_bf16(a0, b0, acc, 0, 0, 0);
        acc = __builtin_amdgcn_mfma_f32_16x16x32_bf16(a1, b1, acc, 0, 0, 0);
        float4 v;
        v.x = fast_exp2(acc[0]) * inv;
        v.y = fast_exp2(acc[1]) * inv;
        v.z = fast_exp2(acc[2]) * inv;
        v.w = fast_exp2(acc[3]) * inv;
        *(float4*)(orow + jt) = v;
    }
}

// ---------------------------------------------------------------------------
// hx projection — only needed when gamma != 0 (never in this bench; early-exit)
// ---------------------------------------------------------------------------
__global__ __launch_bounds__(256) void proj_h(
    const float* __restrict__ x, const float* __restrict__ h_w,
    const float* __restrict__ h_b, const float* __restrict__ gamma,
    float* __restrict__ hx)
{
    if (gamma[0] == 0.0f) return;
    int tid = blockIdx.x * 256 + threadIdx.x;   // 524288 threads
    for (int e = 0; e < 8; ++e) {
        int idx = tid + e * 524288;
        int n = idx & (NN - 1);
        int c = (idx >> 12) & (CC - 1);
        int b = idx >> 21;
        float s = h_b[c];
        for (int cc = 0; cc < CC; ++cc)
            s += h_w[c * CC + cc] * x[((size_t)b * CC + cc) * NN + n];
        hx[idx] = s;
    }
}

// ---------------------------------------------------------------------------
// out = gamma * (hx . attn^T) + x ; gamma==0 fast path: out = x (float4 copy)
// ---------------------------------------------------------------------------
__global__ __launch_bounds__(256) void out_kernel(
    const float* __restrict__ x, const float* __restrict__ gamma,
    const float* __restrict__ hx, const float* __restrict__ attn,
    float* __restrict__ out)
{
    const float g = gamma[0];
    int tid = blockIdx.x * 256 + threadIdx.x;  // 1,048,576 threads
    if (g == 0.0f) {
        ((float4*)out)[tid] = ((const float4*)x)[tid];
    } else {
        for (int e = 0; e < 4; ++e) {
            int idx = tid + e * 1048576;
            int i = idx & (NN - 1);
            int c = (idx >> 12) & (CC - 1);
            int b = idx >> 21;
            const float* hrow = hx + ((size_t)b * CC + c) * NN;
            const float* arow = attn + ((size_t)b * NN + i) * NN;
            float s = 0.0f;
            for (int j = 0; j < NN; ++j) s += hrow[j] * arow[j];
            out[idx] = g * s + x[idx];
        }
    }
}

extern "C" void kernel_launch(void* const* d_in, const int* in_sizes, int n_in,
                              void* d_out, int out_size, void* d_ws, size_t ws_size,
                              hipStream_t stream)
{
    (void)in_sizes; (void)n_in; (void)out_size; (void)ws_size;
    const float* x     = (const float*)d_in[0];
    const float* f_w   = (const float*)d_in[1];
    const float* f_b   = (const float*)d_in[2];
    const float* g_w   = (const float*)d_in[3];
    const float* g_b   = (const float*)d_in[4];
    const float* h_w   = (const float*)d_in[5];
    const float* h_b   = (const float*)d_in[6];
    const float* gamma = (const float*)d_in[7];

    float* out  = (float*)d_out;                 // [B,C,N] = 4,194,304 f32
    float* attn = out + (size_t)BB * CC * NN;    // [B,N,N] = 33,554,432 f32

    char* ws = (char*)d_ws;
    unsigned short* fgT = (unsigned short*)ws;                        // 2 MB
    float* l  = (float*)(ws + (size_t)BB * NN * 128 * 2);             // 32 KB
    float* hx = (float*)(ws + (size_t)BB * NN * 128 * 2 + 65536);     // 16 MB (dead path)

    proj_fg<<<dim3(NN / 32, BB), 256, 0, stream>>>(x, f_w, f_b, g_w, g_b, fgT, l);
    proj_h<<<1024, 256, 0, stream>>>(x, h_w, h_b, gamma, hx);
    attn_rowsum<<<dim3(16, 16, 2), 256, 0, stream>>>(fgT, l);
    attn_write<<<dim3(8, 64, 2), 256, 0, stream>>>(fgT, l, attn);
    out_kernel<<<4096, 256, 0, stream>>>(x, gamma, hx, attn, out);
}